// Round 18
// baseline (121.887 us; speedup 1.0000x reference)
//
#include <hip/hip_runtime.h>
#include <hip/hip_bf16.h>
#include <stdint.h>

#define NEG_INF -9.0e15f
#define LRELU_ALPHA 0.2f
#define LOG2E 1.442695040888963f

using bf16x8  = __attribute__((ext_vector_type(8))) short;
using f32x4   = __attribute__((ext_vector_type(4))) float;
using short4v = __attribute__((ext_vector_type(4))) short;
using int4v   = __attribute__((ext_vector_type(4))) int;
using float4v = __attribute__((ext_vector_type(4))) float;
using uint2v  = __attribute__((ext_vector_type(2))) unsigned;
using uint4v  = __attribute__((ext_vector_type(4))) unsigned;

static __device__ __forceinline__ short f2bf(float f) {
  unsigned u = __builtin_bit_cast(unsigned, f);
  u = u + 0x7FFFu + ((u >> 16) & 1u);   // RNE
  return (short)(u >> 16);
}
static __device__ __forceinline__ unsigned cvtpk_bf16(float lo, float hi) {
  unsigned r;
  asm volatile("v_cvt_pk_bf16_f32 %0, %1, %2" : "=v"(r) : "v"(lo), "v"(hi));
  return r;
}
static __device__ __forceinline__ void gload16(const void* g, void* l) {
  __builtin_amdgcn_global_load_lds((const __attribute__((address_space(1))) void*)g,
                                   (__attribute__((address_space(3))) void*)l, 16, 0, 0);
}

// ---------- prep: blocks 0..15 = W(f32)->W^T(bf16); block 16 = aW1/aW2 = W @ a1/a2 ----------
__global__ __launch_bounds__(256) void prep_kernel(
    const float* __restrict__ W, const float* __restrict__ a,
    short* __restrict__ W_t, float* __restrict__ aW1, float* __restrict__ aW2)
{
  const int bid = blockIdx.x;
  const int tid = threadIdx.x;
  if (bid < 16) {
    __shared__ float t[64][65];
    const int m0 = (bid & 3) * 64, n0 = (bid >> 2) * 64;
    const int rr = tid >> 3, cc = (tid & 7) * 8;
#pragma unroll
    for (int p = 0; p < 2; ++p) {
      int row = rr + p * 32;
      const float* sp = W + (m0 + row) * 256 + n0 + cc;
      float4v v0 = *(const float4v*)sp;
      float4v v1 = *(const float4v*)(sp + 4);
#pragma unroll
      for (int j = 0; j < 4; ++j) { t[row][cc + j] = v0[j]; t[row][cc + 4 + j] = v1[j]; }
    }
    __syncthreads();
#pragma unroll
    for (int p = 0; p < 2; ++p) {
      int orow = rr + p * 32;
      short vv[8] __attribute__((aligned(16)));
#pragma unroll
      for (int j = 0; j < 8; ++j) vv[j] = f2bf(t[cc + j][orow]);
      short* dp = W_t + (n0 + orow) * 256 + m0 + cc;
      *(int4v*)dp = *(const int4v*)vv;
    }
  } else {
    const int r8 = tid >> 3, o4 = (tid & 7) * 4;
    float s1[8] = {}, s2[8] = {};
#pragma unroll
    for (int rp = 0; rp < 8; ++rp) {
      int row = r8 + rp * 32;
#pragma unroll
      for (int k = 0; k < 8; ++k) {
        int o = o4 + k * 32;
        float4v wv = *(const float4v*)(W + row * 256 + o);
        float4v a1 = *(const float4v*)(a + o);
        float4v a2 = *(const float4v*)(a + 256 + o);
#pragma unroll
        for (int e = 0; e < 4; ++e) { s1[rp] += wv[e] * a1[e]; s2[rp] += wv[e] * a2[e]; }
      }
    }
#pragma unroll
    for (int rp = 0; rp < 8; ++rp) {
#pragma unroll
      for (int off = 4; off > 0; off >>= 1) {
        s1[rp] += __shfl_xor(s1[rp], off, 64);
        s2[rp] += __shfl_xor(s2[rp], off, 64);
      }
      if ((tid & 7) == 0) { aW1[r8 + rp * 32] = s1[rp]; aW2[r8 + rp * 32] = s2[rp]; }
    }
  }
}

// ---------- Wh_t = (cast(h) @ W)^T per batch, with FUSED e1/e2 = h @ aW (y==0 blocks) ----------
__global__ __launch_bounds__(256) void gemm_h_kernel(
    const float* __restrict__ A, const short* __restrict__ Bt,
    short* __restrict__ Wht, const float* __restrict__ aW1,
    const float* __restrict__ aW2, float* __restrict__ e1, float* __restrict__ e2)
{
  __shared__ short As[128 * 32];
  __shared__ short Bs[128 * 32];
  __shared__ short T[128][136];
  const int m0 = blockIdx.x * 128, n0 = blockIdx.y * 128;
  const int tid = threadIdx.x;
  const int w = tid >> 6, lane = tid & 63;
  const int wr = w >> 1, wc = w & 1;
  const int g = lane >> 4, lr = lane & 15;
  const bool doE = (blockIdx.y == 0);

  f32x4 acc[4][4] = {};
  float s1q[2] = {0.f, 0.f}, s2q[2] = {0.f, 0.f};

  for (int k0 = 0; k0 < 256; k0 += 32) {
    __syncthreads();
#pragma unroll
    for (int q = 0; q < 2; ++q) {
      int c = q * 256 + tid;
      int row = c >> 2, kq = (c & 3) << 3;
      const float* ap = A + (long long)(m0 + row) * 256 + k0 + kq;
      float4v u0 = *(const float4v*)ap;
      float4v u1 = *(const float4v*)(ap + 4);
      if (doE) {
        float4v w1a = *(const float4v*)(aW1 + k0 + kq);
        float4v w1b = *(const float4v*)(aW1 + k0 + kq + 4);
        float4v w2a = *(const float4v*)(aW2 + k0 + kq);
        float4v w2b = *(const float4v*)(aW2 + k0 + kq + 4);
#pragma unroll
        for (int e = 0; e < 4; ++e) {
          s1q[q] += u0[e] * w1a[e] + u1[e] * w1b[e];
          s2q[q] += u0[e] * w2a[e] + u1[e] * w2b[e];
        }
      }
      uint4v uv;
      uv[0] = cvtpk_bf16(u0[0], u0[1]);
      uv[1] = cvtpk_bf16(u0[2], u0[3]);
      uv[2] = cvtpk_bf16(u1[0], u1[1]);
      uv[3] = cvtpk_bf16(u1[2], u1[3]);
      *(bf16x8*)(As + c * 8) = __builtin_bit_cast(bf16x8, uv);
    }
#pragma unroll
    for (int q = 0; q < 2; ++q) {
      int p = w * 2 + q;
      int c = p * 64 + lane;
      int row = c >> 2, kq = (c & 3) << 3;
      gload16(Bt + (long long)(n0 + row) * 256 + k0 + kq, Bs + p * 512);
    }
    __syncthreads();

    bf16x8 af[4], bfr[4];
#pragma unroll
    for (int i = 0; i < 4; ++i) {
      af[i]  = *(const bf16x8*)(As + (wr * 64 + i * 16 + lr) * 32 + 8 * g);
      bfr[i] = *(const bf16x8*)(Bs + (wc * 64 + i * 16 + lr) * 32 + 8 * g);
    }
#pragma unroll
    for (int i = 0; i < 4; ++i)
#pragma unroll
      for (int j = 0; j < 4; ++j)
        acc[i][j] = __builtin_amdgcn_mfma_f32_16x16x32_bf16(af[i], bfr[j], acc[i][j], 0, 0, 0);
  }

  if (doE) {
#pragma unroll
    for (int q = 0; q < 2; ++q) {
      float a1 = s1q[q], a2 = s2q[q];
      a1 += __shfl_xor(a1, 1, 64); a1 += __shfl_xor(a1, 2, 64);
      a2 += __shfl_xor(a2, 1, 64); a2 += __shfl_xor(a2, 2, 64);
      if ((tid & 3) == 0) {
        int row = m0 + q * 64 + (tid >> 2);
        e1[row] = a1; e2[row] = a2;
      }
    }
  }

  __syncthreads();
#pragma unroll
  for (int i = 0; i < 4; ++i) {
    int row_base = wr * 64 + i * 16 + 4 * g;
#pragma unroll
    for (int j = 0; j < 4; ++j) {
      int col = wc * 64 + j * 16 + lr;
#pragma unroll
      for (int r = 0; r < 4; ++r)
        T[col][row_base + r] = f2bf(acc[i][j][r]);
    }
  }
  __syncthreads();
  const int b = m0 >> 11, mloc = m0 & 2047;
  short* wb = Wht + (long long)b * 524288 + mloc;
#pragma unroll
  for (int p = 0; p < 8; ++p) {
    int c = (tid >> 4) + p * 16;
    int off = (tid & 15) * 8;
    bf16x8 v = *(const bf16x8*)(&T[c][off]);
    *(bf16x8*)(wb + (long long)(n0 + c) * 2048 + off) = v;
  }
}

// ---------- pass 1: masked softmax -> NORMALIZED P as bf16 into the UPPER HALF of each
// attention row of d_out (2048 bf16 in the top 1024 f32 slots). R5-proven softmax body;
// empty rows fall out naturally (exp(0)=1 -> uniform 1/2048). ----------
__global__ __launch_bounds__(256) void pack_kernel(
    const int* __restrict__ adj, const float* __restrict__ e1,
    const float* __restrict__ e2, float* __restrict__ attn)
{
  const int i = blockIdx.x;
  const int b = blockIdx.y;
  const long long row = (long long)b * 2048 + i;
  const int tid = threadIdx.x;
  const int wid = tid >> 6, lane = tid & 63;
  const int j0 = tid * 8;

  const int*   arow = adj + row * 2048 + j0;
  const float  ei   = e1[row];
  const float* e2b  = e2 + b * 2048 + j0;

  int4v   a0 = *(const int4v*)(arow);
  int4v   a1 = *(const int4v*)(arow + 4);
  float4v f0 = *(const float4v*)(e2b);
  float4v f1 = *(const float4v*)(e2b + 4);

  float s[8];
#pragma unroll
  for (int k = 0; k < 8; ++k) {
    float x = ei + (k < 4 ? f0[k] : f1[k - 4]);
    float v = fmaxf(x, LRELU_ALPHA * x);
    int  ad = (k < 4 ? a0[k] : a1[k - 4]);
    s[k] = (ad > 0) ? v : NEG_INF;
  }
  float m = s[0];
#pragma unroll
  for (int k = 1; k < 8; ++k) m = fmaxf(m, s[k]);
#pragma unroll
  for (int off = 32; off > 0; off >>= 1) m = fmaxf(m, __shfl_xor(m, off, 64));

  __shared__ float wmax[4], wsum[4];
  if (lane == 0) wmax[wid] = m;
  __syncthreads();
  const float M = fmaxf(fmaxf(wmax[0], wmax[1]), fmaxf(wmax[2], wmax[3]));

  float p[8]; float t = 0.f;
#pragma unroll
  for (int k = 0; k < 8; ++k) { p[k] = __expf(s[k] - M); t += p[k]; }
#pragma unroll
  for (int off = 32; off > 0; off >>= 1) t += __shfl_xor(t, off, 64);
  if (lane == 0) wsum[wid] = t;
  __syncthreads();
  const float S = wsum[0] + wsum[1] + wsum[2] + wsum[3];
  const float r = 1.0f / S;

  uint4v uv;
  uv[0] = cvtpk_bf16(p[0] * r, p[1] * r);
  uv[1] = cvtpk_bf16(p[2] * r, p[3] * r);
  uv[2] = cvtpk_bf16(p[4] * r, p[5] * r);
  uv[3] = cvtpk_bf16(p[6] * r, p[7] * r);
  short* op = (short*)(attn + row * 2048 + 1024) + j0;
  *(uint4v*)op = uv;
}

// ---------- pass 2: LEAN GEMM. A (P-bf16) via DMA from attn upper-half; attention f32
// produced by bit-expanding the A tile; B via DMA (R12 swizzles). 36 KB LDS -> 4 blocks/CU.
// Aliasing safety: expand(t) writes f32 slots [32t,32t+32); A-DMA(t') reads slots
// [1024+16t',+16) -> collision only at t'=2t-64, whose DMA completed a barrier earlier.
__global__ __launch_bounds__(256, 4) void pv_kernel(
    const short* __restrict__ Bt, float* __restrict__ attnw, float* __restrict__ C)
{
  __shared__ short As0[32 * 32],  As1[32 * 32];     // 2 x 2 KB
  __shared__ short Bs0[256 * 32], Bs1[256 * 32];    // 2 x 16 KB
  const int bid = blockIdx.x;
  const int bz  = bid & 7;          // XCD-pinned batch
  const int M0  = (bid >> 3) << 5;
  const int tid = threadIdx.x;
  const int w = tid >> 6, lane = tid & 63;
  const int g = lane >> 4, lr = lane & 15;

  Bt    += (long long)bz * 524288;
  attnw += (long long)bz * 4194304;
  C     += (long long)bz * 524288;

  // expand identities: thread (pr, k4) owns 4 P values of row M0+pr
  const int pr = tid >> 3, k4 = (tid & 7) << 2;
  const int kc = k4 >> 3;
  const int as_off = pr * 32 + ((kc ^ ((pr >> 1) & 3)) << 3) + (k4 & 7);
  float* arow = attnw + (long long)(M0 + pr) * 2048;

  // B-stage identities (R12-verbatim)
  const int bcol_off = lane >> 2;
  const int bchunk   = (lane & 3) ^ ((lane >> 3) & 3);

  // A-stage (waves 0,1 only): slot s = w*64+lane -> row r=s>>2, LDS chunk cs=s&3
  // holds data chunk dc = cs ^ ((r>>1)&3); source = P-upper of row M0+r.
  const int a_s  = w * 64 + lane;
  const int a_r  = a_s >> 2, a_cs = a_s & 3;
  const int a_dc = a_cs ^ ((a_r >> 1) & 3);
  const short* aP = (const short*)(attnw + (long long)(M0 + a_r) * 2048 + 1024) + a_dc * 8;

  f32x4 acc[2][4] = {};

  auto STAGE = [&](short* BsD, short* AsD, int k0) {
#pragma unroll
    for (int q = 0; q < 4; ++q) {
      int pp = w * 4 + q;
      int col = pp * 16 + bcol_off;
      gload16(Bt + (long long)col * 2048 + k0 + bchunk * 8, BsD + pp * 512);
    }
    if (w < 2) gload16(aP + k0, AsD + w * 512);     // 2 x 1024 B covers the 2 KB A tile
  };

  auto COMPUTE = [&](const short* BsD, const short* AsD, int k0) {
    // expand this tile's P to f32 attention (bf16<<16), fire-and-forget store
    uint2v pw = *(const uint2v*)(AsD + as_off);
    float4v o;
    o[0] = __builtin_bit_cast(float, pw[0] << 16);
    o[1] = __builtin_bit_cast(float, pw[0] & 0xFFFF0000u);
    o[2] = __builtin_bit_cast(float, pw[1] << 16);
    o[3] = __builtin_bit_cast(float, pw[1] & 0xFFFF0000u);
    *(float4v*)(arow + k0 + k4) = o;

    bf16x8 af[2], bfr[4];
#pragma unroll
    for (int i = 0; i < 2; ++i) {
      int row = i * 16 + lr;
      af[i] = *(const bf16x8*)(AsD + row * 32 + ((g ^ ((row >> 1) & 3)) << 3));
    }
#pragma unroll
    for (int j = 0; j < 4; ++j) {
      int col = w * 64 + j * 16 + lr;
      bfr[j] = *(const bf16x8*)(BsD + col * 32 + ((g ^ ((col >> 1) & 3)) << 3));
    }
#pragma unroll
    for (int i = 0; i < 2; ++i)
#pragma unroll
      for (int j = 0; j < 4; ++j)
        acc[i][j] = __builtin_amdgcn_mfma_f32_16x16x32_bf16(af[i], bfr[j], acc[i][j], 0, 0, 0);
  };

  STAGE(Bs0, As0, 0);
  __syncthreads();
  for (int t = 0; t < 64; t += 2) {
    STAGE(Bs1, As1, (t + 1) * 32);
    COMPUTE(Bs0, As0, t * 32);
    __syncthreads();
    if (t + 2 < 64) STAGE(Bs0, As0, (t + 2) * 32);
    COMPUTE(Bs1, As1, (t + 1) * 32);
    __syncthreads();
  }

  // C/D: col=lane&15, row=(lane>>4)*4+reg  [m89]
#pragma unroll
  for (int i = 0; i < 2; ++i) {
    int row_base = M0 + i * 16 + 4 * g;
#pragma unroll
    for (int j = 0; j < 4; ++j) {
      int col = w * 64 + j * 16 + lr;
#pragma unroll
      for (int r = 0; r < 4; ++r) {
        float v = acc[i][j][r];
        v = (v > 0.f) ? v : (__expf(v) - 1.f);   // ELU
        C[(long long)(row_base + r) * 256 + col] = v;
      }
    }
  }
}

extern "C" void kernel_launch(void* const* d_in, const int* in_sizes, int n_in,
                              void* d_out, int out_size, void* d_ws, size_t ws_size,
                              hipStream_t stream)
{
  const float* h   = (const float*)d_in[0];   // (8,2048,256) f32
  const int*   adj = (const int*)d_in[1];     // (8,2048,2048) int32
  const float* W   = (const float*)d_in[2];   // (256,256) f32
  const float* a   = (const float*)d_in[3];   // (512,1) f32

  float* hp_out   = (float*)d_out;            // elu(h_prime): 4,194,304 f32
  float* attn_out = hp_out + 4194304LL;       // attention: 33,554,432 f32

  // workspace: ~8.7 MB
  short* W_t  = (short*)d_ws;                 // 65,536 shorts
  short* Wh_t = W_t + 65536;                  // 8 x (256x2048) shorts (8.39 MB)
  float* e1   = (float*)(Wh_t + 4194304);     // 16384
  float* e2   = e1 + 16384;
  float* aW1  = e2 + 16384;                   // 256
  float* aW2  = aW1 + 256;                    // 256

  // 1) W^T (bf16) + aW1/aW2 = W @ a1/a2
  prep_kernel<<<17, 256, 0, stream>>>(W, a, W_t, aW1, aW2);
  // 2) Wh_t = (cast(h) @ W)^T with fused e1/e2 = h @ aW
  gemm_h_kernel<<<dim3(128, 2), 256, 0, stream>>>(h, W_t, Wh_t, aW1, aW2, e1, e2);
  // 3) masked softmax -> normalized P (bf16) staged in attn rows' upper halves
  pack_kernel<<<dim3(2048, 8), 256, 0, stream>>>(adj, e1, e2, attn_out);
  // 4) lean GEMM: P-bf16 DMA -> {attention f32 expand, P @ Wh_t + ELU}
  pv_kernel<<<512, 256, 0, stream>>>(Wh_t, attn_out, hp_out);
}

// Round 19
// 121.560 us; speedup vs baseline: 1.0027x; 1.0027x over previous
//
#include <hip/hip_runtime.h>
#include <hip/hip_bf16.h>
#include <stdint.h>

#define NEG_INF -9.0e15f
#define LRELU_ALPHA 0.2f
#define LOG2E 1.442695040888963f

using bf16x8  = __attribute__((ext_vector_type(8))) short;
using f32x4   = __attribute__((ext_vector_type(4))) float;
using short4v = __attribute__((ext_vector_type(4))) short;
using int4v   = __attribute__((ext_vector_type(4))) int;
using float4v = __attribute__((ext_vector_type(4))) float;
using uint2v  = __attribute__((ext_vector_type(2))) unsigned;
using uint4v  = __attribute__((ext_vector_type(4))) unsigned;

static __device__ __forceinline__ short f2bf(float f) {
  unsigned u = __builtin_bit_cast(unsigned, f);
  u = u + 0x7FFFu + ((u >> 16) & 1u);   // RNE
  return (short)(u >> 16);
}
static __device__ __forceinline__ unsigned cvtpk_bf16(float lo, float hi) {
  unsigned r;
  asm volatile("v_cvt_pk_bf16_f32 %0, %1, %2" : "=v"(r) : "v"(lo), "v"(hi));
  return r;
}
static __device__ __forceinline__ void gload16(const void* g, void* l) {
  __builtin_amdgcn_global_load_lds((const __attribute__((address_space(1))) void*)g,
                                   (__attribute__((address_space(3))) void*)l, 16, 0, 0);
}

// ---------- prep: blocks 0..15 = W(f32)->W^T(bf16); block 16 = aW1/aW2 = W @ a1/a2 ----------
__global__ __launch_bounds__(256) void prep_kernel(
    const float* __restrict__ W, const float* __restrict__ a,
    short* __restrict__ W_t, float* __restrict__ aW1, float* __restrict__ aW2)
{
  const int bid = blockIdx.x;
  const int tid = threadIdx.x;
  if (bid < 16) {
    __shared__ float t[64][65];
    const int m0 = (bid & 3) * 64, n0 = (bid >> 2) * 64;
    const int rr = tid >> 3, cc = (tid & 7) * 8;
#pragma unroll
    for (int p = 0; p < 2; ++p) {
      int row = rr + p * 32;
      const float* sp = W + (m0 + row) * 256 + n0 + cc;
      float4v v0 = *(const float4v*)sp;
      float4v v1 = *(const float4v*)(sp + 4);
#pragma unroll
      for (int j = 0; j < 4; ++j) { t[row][cc + j] = v0[j]; t[row][cc + 4 + j] = v1[j]; }
    }
    __syncthreads();
#pragma unroll
    for (int p = 0; p < 2; ++p) {
      int orow = rr + p * 32;
      short vv[8] __attribute__((aligned(16)));
#pragma unroll
      for (int j = 0; j < 8; ++j) vv[j] = f2bf(t[cc + j][orow]);
      short* dp = W_t + (n0 + orow) * 256 + m0 + cc;
      *(int4v*)dp = *(const int4v*)vv;
    }
  } else {
    const int r8 = tid >> 3, o4 = (tid & 7) * 4;
    float s1[8] = {}, s2[8] = {};
#pragma unroll
    for (int rp = 0; rp < 8; ++rp) {
      int row = r8 + rp * 32;
#pragma unroll
      for (int k = 0; k < 8; ++k) {
        int o = o4 + k * 32;
        float4v wv = *(const float4v*)(W + row * 256 + o);
        float4v a1 = *(const float4v*)(a + o);
        float4v a2 = *(const float4v*)(a + 256 + o);
#pragma unroll
        for (int e = 0; e < 4; ++e) { s1[rp] += wv[e] * a1[e]; s2[rp] += wv[e] * a2[e]; }
      }
    }
#pragma unroll
    for (int rp = 0; rp < 8; ++rp) {
#pragma unroll
      for (int off = 4; off > 0; off >>= 1) {
        s1[rp] += __shfl_xor(s1[rp], off, 64);
        s2[rp] += __shfl_xor(s2[rp], off, 64);
      }
      if ((tid & 7) == 0) { aW1[r8 + rp * 32] = s1[rp]; aW2[r8 + rp * 32] = s2[rp]; }
    }
  }
}

// ---------- Wh_t = (cast(h) @ W)^T per batch, with FUSED e1/e2 = h @ aW (y==0 blocks) ----------
__global__ __launch_bounds__(256) void gemm_h_kernel(
    const float* __restrict__ A, const short* __restrict__ Bt,
    short* __restrict__ Wht, const float* __restrict__ aW1,
    const float* __restrict__ aW2, float* __restrict__ e1, float* __restrict__ e2)
{
  __shared__ short As[128 * 32];
  __shared__ short Bs[128 * 32];
  __shared__ short T[128][136];
  const int m0 = blockIdx.x * 128, n0 = blockIdx.y * 128;
  const int tid = threadIdx.x;
  const int w = tid >> 6, lane = tid & 63;
  const int wr = w >> 1, wc = w & 1;
  const int g = lane >> 4, lr = lane & 15;
  const bool doE = (blockIdx.y == 0);

  f32x4 acc[4][4] = {};
  float s1q[2] = {0.f, 0.f}, s2q[2] = {0.f, 0.f};

  for (int k0 = 0; k0 < 256; k0 += 32) {
    __syncthreads();
#pragma unroll
    for (int q = 0; q < 2; ++q) {
      int c = q * 256 + tid;
      int row = c >> 2, kq = (c & 3) << 3;
      const float* ap = A + (long long)(m0 + row) * 256 + k0 + kq;
      float4v u0 = *(const float4v*)ap;
      float4v u1 = *(const float4v*)(ap + 4);
      if (doE) {
        float4v w1a = *(const float4v*)(aW1 + k0 + kq);
        float4v w1b = *(const float4v*)(aW1 + k0 + kq + 4);
        float4v w2a = *(const float4v*)(aW2 + k0 + kq);
        float4v w2b = *(const float4v*)(aW2 + k0 + kq + 4);
#pragma unroll
        for (int e = 0; e < 4; ++e) {
          s1q[q] += u0[e] * w1a[e] + u1[e] * w1b[e];
          s2q[q] += u0[e] * w2a[e] + u1[e] * w2b[e];
        }
      }
      uint4v uv;
      uv[0] = cvtpk_bf16(u0[0], u0[1]);
      uv[1] = cvtpk_bf16(u0[2], u0[3]);
      uv[2] = cvtpk_bf16(u1[0], u1[1]);
      uv[3] = cvtpk_bf16(u1[2], u1[3]);
      *(bf16x8*)(As + c * 8) = __builtin_bit_cast(bf16x8, uv);
    }
#pragma unroll
    for (int q = 0; q < 2; ++q) {
      int p = w * 2 + q;
      int c = p * 64 + lane;
      int row = c >> 2, kq = (c & 3) << 3;
      gload16(Bt + (long long)(n0 + row) * 256 + k0 + kq, Bs + p * 512);
    }
    __syncthreads();

    bf16x8 af[4], bfr[4];
#pragma unroll
    for (int i = 0; i < 4; ++i) {
      af[i]  = *(const bf16x8*)(As + (wr * 64 + i * 16 + lr) * 32 + 8 * g);
      bfr[i] = *(const bf16x8*)(Bs + (wc * 64 + i * 16 + lr) * 32 + 8 * g);
    }
#pragma unroll
    for (int i = 0; i < 4; ++i)
#pragma unroll
      for (int j = 0; j < 4; ++j)
        acc[i][j] = __builtin_amdgcn_mfma_f32_16x16x32_bf16(af[i], bfr[j], acc[i][j], 0, 0, 0);
  }

  if (doE) {
#pragma unroll
    for (int q = 0; q < 2; ++q) {
      float a1 = s1q[q], a2 = s2q[q];
      a1 += __shfl_xor(a1, 1, 64); a1 += __shfl_xor(a1, 2, 64);
      a2 += __shfl_xor(a2, 1, 64); a2 += __shfl_xor(a2, 2, 64);
      if ((tid & 3) == 0) {
        int row = m0 + q * 64 + (tid >> 2);
        e1[row] = a1; e2[row] = a2;
      }
    }
  }

  __syncthreads();
#pragma unroll
  for (int i = 0; i < 4; ++i) {
    int row_base = wr * 64 + i * 16 + 4 * g;
#pragma unroll
    for (int j = 0; j < 4; ++j) {
      int col = wc * 64 + j * 16 + lr;
#pragma unroll
      for (int r = 0; r < 4; ++r)
        T[col][row_base + r] = f2bf(acc[i][j][r]);
    }
  }
  __syncthreads();
  const int b = m0 >> 11, mloc = m0 & 2047;
  short* wb = Wht + (long long)b * 524288 + mloc;
#pragma unroll
  for (int p = 0; p < 8; ++p) {
    int c = (tid >> 4) + p * 16;
    int off = (tid & 15) * 8;
    bf16x8 v = *(const bf16x8*)(&T[c][off]);
    *(bf16x8*)(wb + (long long)(n0 + c) * 2048 + off) = v;
  }
}

// ------------- masked leakyrelu + row softmax -> attention f32 (R5-verbatim, BW-roofline) ------
__global__ __launch_bounds__(256) void attn_softmax_kernel(
    const int* __restrict__ adj, const float* __restrict__ e1,
    const float* __restrict__ e2, float* __restrict__ attn)
{
  const int i = blockIdx.x;
  const int b = blockIdx.y;
  const long long row = (long long)b * 2048 + i;
  const int tid = threadIdx.x;
  const int wid = tid >> 6, lane = tid & 63;
  const int j0 = tid * 8;

  const int*   arow = adj + row * 2048 + j0;
  const float  ei   = e1[row];
  const float* e2b  = e2 + b * 2048 + j0;

  int4v   a0 = *(const int4v*)(arow);
  int4v   a1 = *(const int4v*)(arow + 4);
  float4v f0 = *(const float4v*)(e2b);
  float4v f1 = *(const float4v*)(e2b + 4);

  float s[8];
#pragma unroll
  for (int k = 0; k < 8; ++k) {
    float x = ei + (k < 4 ? f0[k] : f1[k - 4]);
    float v = x > 0.f ? x : LRELU_ALPHA * x;
    int  ad = (k < 4 ? a0[k] : a1[k - 4]);
    s[k] = (ad > 0) ? v : NEG_INF;
  }
  float m = s[0];
#pragma unroll
  for (int k = 1; k < 8; ++k) m = fmaxf(m, s[k]);
#pragma unroll
  for (int off = 32; off > 0; off >>= 1) m = fmaxf(m, __shfl_xor(m, off, 64));

  __shared__ float wmax[4], wsum[4];
  if (lane == 0) wmax[wid] = m;
  __syncthreads();
  const float M = fmaxf(fmaxf(wmax[0], wmax[1]), fmaxf(wmax[2], wmax[3]));

  float p[8]; float t = 0.f;
#pragma unroll
  for (int k = 0; k < 8; ++k) { p[k] = __expf(s[k] - M); t += p[k]; }
#pragma unroll
  for (int off = 32; off > 0; off >>= 1) t += __shfl_xor(t, off, 64);
  if (lane == 0) wsum[wid] = t;
  __syncthreads();
  const float S = wsum[0] + wsum[1] + wsum[2] + wsum[3];
  const float r = 1.0f / S;

  float4v o0, o1;
#pragma unroll
  for (int k = 0; k < 4; ++k) { o0[k] = p[k] * r; o1[k] = p[k + 4] * r; }
  float* op = attn + row * 2048 + j0;
  *(float4v*)op       = o0;
  *(float4v*)(op + 4) = o1;
}

// ---------- pv: PURE-READ GEMM. A = f32 attention via DMA (chunk-swz ^(r&7), pre-swz source),
// cvt_pk -> bf16 fragments after LDS read; B = R12-verbatim. NO global stores in the K-loop
// (R18 measured pv-with-stores at 84.8 us; barrier vmcnt drain of store-acks was the cost).
// LDS 40 KB. Epilogue C-write (ELU) only. ----------
__global__ __launch_bounds__(256, 3) void pv_kernel(
    const float* __restrict__ attn, const short* __restrict__ Bt, float* __restrict__ C)
{
  __shared__ float As0[32 * 32], As1[32 * 32];      // 2 x 4 KB (f32 tiles)
  __shared__ short Bs0[256 * 32], Bs1[256 * 32];    // 2 x 16 KB
  const int bid = blockIdx.x;
  const int bz  = bid & 7;          // XCD-pinned batch
  const int M0  = (bid >> 3) << 5;
  const int tid = threadIdx.x;
  const int w = tid >> 6, lane = tid & 63;
  const int g = lane >> 4, lr = lane & 15;

  attn += (long long)bz * 4194304;
  Bt   += (long long)bz * 524288;
  C    += (long long)bz * 524288;

  // A-stage: issue p=w (1 KB each, 4 waves cover the 4 KB tile):
  // slot s=p*64+lane -> row r=s>>3, slot-chunk cs=s&7 (16B f32 chunks, 8/row);
  // fetch global chunk dc = cs ^ (r&7)  [involution; read side applies the same XOR]
  const int a_s  = w * 64 + lane;
  const int a_r  = a_s >> 3, a_cs = a_s & 7;
  const int a_dc = a_cs ^ (a_r & 7);
  const float* aSrc = attn + (long long)(M0 + a_r) * 2048 + a_dc * 4;

  // B-stage identities (R12-verbatim)
  const int bcol_off = lane >> 2;
  const int bchunk   = (lane & 3) ^ ((lane >> 3) & 3);

  f32x4 acc[2][4] = {};

  auto STAGE = [&](short* BsD, float* AsD, int k0) {
#pragma unroll
    for (int q = 0; q < 4; ++q) {
      int pp = w * 4 + q;
      int col = pp * 16 + bcol_off;
      gload16(Bt + (long long)col * 2048 + k0 + bchunk * 8, BsD + pp * 512);
    }
    gload16(aSrc + k0, (char*)AsD + w * 1024);
  };

  auto COMPUTE = [&](const short* BsD, const float* AsD) {
    bf16x8 af[2], bfr[4];
#pragma unroll
    for (int i = 0; i < 2; ++i) {
      int row = i * 16 + lr;
      const float* ar = AsD + row * 32;
      float4v lo = *(const float4v*)(ar + (((2 * g)     ^ (row & 7)) << 2));
      float4v hi = *(const float4v*)(ar + (((2 * g + 1) ^ (row & 7)) << 2));
      uint4v uv;
      uv[0] = cvtpk_bf16(lo[0], lo[1]);
      uv[1] = cvtpk_bf16(lo[2], lo[3]);
      uv[2] = cvtpk_bf16(hi[0], hi[1]);
      uv[3] = cvtpk_bf16(hi[2], hi[3]);
      af[i] = __builtin_bit_cast(bf16x8, uv);
    }
#pragma unroll
    for (int j = 0; j < 4; ++j) {
      int col = w * 64 + j * 16 + lr;
      bfr[j] = *(const bf16x8*)(BsD + col * 32 + ((g ^ ((col >> 1) & 3)) << 3));
    }
#pragma unroll
    for (int i = 0; i < 2; ++i)
#pragma unroll
      for (int j = 0; j < 4; ++j)
        acc[i][j] = __builtin_amdgcn_mfma_f32_16x16x32_bf16(af[i], bfr[j], acc[i][j], 0, 0, 0);
  };

  STAGE(Bs0, As0, 0);
  __syncthreads();
  for (int t = 0; t < 64; t += 2) {
    STAGE(Bs1, As1, (t + 1) * 32);
    COMPUTE(Bs0, As0);
    __syncthreads();
    if (t + 2 < 64) STAGE(Bs0, As0, (t + 2) * 32);
    COMPUTE(Bs1, As1);
    __syncthreads();
  }

  // C/D: col=lane&15, row=(lane>>4)*4+reg  [m89]
#pragma unroll
  for (int i = 0; i < 2; ++i) {
    int row_base = M0 + i * 16 + 4 * g;
#pragma unroll
    for (int j = 0; j < 4; ++j) {
      int col = w * 64 + j * 16 + lr;
#pragma unroll
      for (int r = 0; r < 4; ++r) {
        float v = acc[i][j][r];
        v = (v > 0.f) ? v : (__expf(v) - 1.f);   // ELU
        C[(long long)(row_base + r) * 256 + col] = v;
      }
    }
  }
}

extern "C" void kernel_launch(void* const* d_in, const int* in_sizes, int n_in,
                              void* d_out, int out_size, void* d_ws, size_t ws_size,
                              hipStream_t stream)
{
  const float* h   = (const float*)d_in[0];   // (8,2048,256) f32
  const int*   adj = (const int*)d_in[1];     // (8,2048,2048) int32
  const float* W   = (const float*)d_in[2];   // (256,256) f32
  const float* a   = (const float*)d_in[3];   // (512,1) f32

  float* hp_out   = (float*)d_out;            // elu(h_prime): 4,194,304 f32
  float* attn_out = hp_out + 4194304LL;       // attention: 33,554,432 f32

  // workspace: ~8.7 MB
  short* W_t  = (short*)d_ws;                 // 65,536 shorts
  short* Wh_t = W_t + 65536;                  // 8 x (256x2048) shorts (8.39 MB)
  float* e1   = (float*)(Wh_t + 4194304);     // 16384
  float* e2   = e1 + 16384;
  float* aW1  = e2 + 16384;                   // 256
  float* aW2  = aW1 + 256;                    // 256

  // 1) W^T (bf16) + aW1/aW2 = W @ a1/a2
  prep_kernel<<<17, 256, 0, stream>>>(W, a, W_t, aW1, aW2);
  // 2) Wh_t = (cast(h) @ W)^T with fused e1/e2 = h @ aW
  gemm_h_kernel<<<dim3(128, 2), 256, 0, stream>>>(h, W_t, Wh_t, aW1, aW2, e1, e2);
  // 3) masked softmax -> final f32 attention (BW-roofline, fire-and-forget stores)
  attn_softmax_kernel<<<dim3(2048, 8), 256, 0, stream>>>(adj, e1, e2, attn_out);
  // 4) pure-read GEMM: attention(f32) @ Wh_t + ELU -> h_prime
  pv_kernel<<<512, 256, 0, stream>>>(attn_out, Wh_t, hp_out);
}

// Round 20
// 113.933 us; speedup vs baseline: 1.0698x; 1.0669x over previous
//
#include <hip/hip_runtime.h>
#include <hip/hip_bf16.h>
#include <stdint.h>

#define NEG_INF -9.0e15f
#define LRELU_ALPHA 0.2f

using bf16x8  = __attribute__((ext_vector_type(8))) short;
using f32x4   = __attribute__((ext_vector_type(4))) float;
using short4v = __attribute__((ext_vector_type(4))) short;
using int4v   = __attribute__((ext_vector_type(4))) int;
using float4v = __attribute__((ext_vector_type(4))) float;
using uint4v  = __attribute__((ext_vector_type(4))) unsigned;

static __device__ __forceinline__ short f2bf(float f) {
  unsigned u = __builtin_bit_cast(unsigned, f);
  u = u + 0x7FFFu + ((u >> 16) & 1u);   // RNE
  return (short)(u >> 16);
}
static __device__ __forceinline__ unsigned cvtpk_bf16(float lo, float hi) {
  unsigned r;
  asm volatile("v_cvt_pk_bf16_f32 %0, %1, %2" : "=v"(r) : "v"(lo), "v"(hi));
  return r;
}
static __device__ __forceinline__ void gload16(const void* g, void* l) {
  __builtin_amdgcn_global_load_lds((const __attribute__((address_space(1))) void*)g,
                                   (__attribute__((address_space(3))) void*)l, 16, 0, 0);
}

// ---------- prep: blocks 0..15 = W(f32)->W^T(bf16); block 16 = aW1/aW2 = W @ a1/a2 ----------
__global__ __launch_bounds__(256) void prep_kernel(
    const float* __restrict__ W, const float* __restrict__ a,
    short* __restrict__ W_t, float* __restrict__ aW1, float* __restrict__ aW2)
{
  const int bid = blockIdx.x;
  const int tid = threadIdx.x;
  if (bid < 16) {
    __shared__ float t[64][65];
    const int m0 = (bid & 3) * 64, n0 = (bid >> 2) * 64;
    const int rr = tid >> 3, cc = (tid & 7) * 8;
#pragma unroll
    for (int p = 0; p < 2; ++p) {
      int row = rr + p * 32;
      const float* sp = W + (m0 + row) * 256 + n0 + cc;
      float4v v0 = *(const float4v*)sp;
      float4v v1 = *(const float4v*)(sp + 4);
#pragma unroll
      for (int j = 0; j < 4; ++j) { t[row][cc + j] = v0[j]; t[row][cc + 4 + j] = v1[j]; }
    }
    __syncthreads();
#pragma unroll
    for (int p = 0; p < 2; ++p) {
      int orow = rr + p * 32;
      short vv[8] __attribute__((aligned(16)));
#pragma unroll
      for (int j = 0; j < 8; ++j) vv[j] = f2bf(t[cc + j][orow]);
      short* dp = W_t + (n0 + orow) * 256 + m0 + cc;
      *(int4v*)dp = *(const int4v*)vv;
    }
  } else {
    const int r8 = tid >> 3, o4 = (tid & 7) * 4;
    float s1[8] = {}, s2[8] = {};
#pragma unroll
    for (int rp = 0; rp < 8; ++rp) {
      int row = r8 + rp * 32;
#pragma unroll
      for (int k = 0; k < 8; ++k) {
        int o = o4 + k * 32;
        float4v wv = *(const float4v*)(W + row * 256 + o);
        float4v a1 = *(const float4v*)(a + o);
        float4v a2 = *(const float4v*)(a + 256 + o);
#pragma unroll
        for (int e = 0; e < 4; ++e) { s1[rp] += wv[e] * a1[e]; s2[rp] += wv[e] * a2[e]; }
      }
    }
#pragma unroll
    for (int rp = 0; rp < 8; ++rp) {
#pragma unroll
      for (int off = 4; off > 0; off >>= 1) {
        s1[rp] += __shfl_xor(s1[rp], off, 64);
        s2[rp] += __shfl_xor(s2[rp], off, 64);
      }
      if ((tid & 7) == 0) { aW1[r8 + rp * 32] = s1[rp]; aW2[r8 + rp * 32] = s2[rp]; }
    }
  }
}

// ---------- Wh_t = (cast(h) @ W)^T per batch, with FUSED e1/e2 = h @ aW (y==0 blocks) ----------
__global__ __launch_bounds__(256) void gemm_h_kernel(
    const float* __restrict__ A, const short* __restrict__ Bt,
    short* __restrict__ Wht, const float* __restrict__ aW1,
    const float* __restrict__ aW2, float* __restrict__ e1, float* __restrict__ e2)
{
  __shared__ short As[128 * 32];
  __shared__ short Bs[128 * 32];
  __shared__ short T[128][136];
  const int m0 = blockIdx.x * 128, n0 = blockIdx.y * 128;
  const int tid = threadIdx.x;
  const int w = tid >> 6, lane = tid & 63;
  const int wr = w >> 1, wc = w & 1;
  const int g = lane >> 4, lr = lane & 15;
  const bool doE = (blockIdx.y == 0);

  f32x4 acc[4][4] = {};
  float s1q[2] = {0.f, 0.f}, s2q[2] = {0.f, 0.f};

  for (int k0 = 0; k0 < 256; k0 += 32) {
    __syncthreads();
#pragma unroll
    for (int q = 0; q < 2; ++q) {
      int c = q * 256 + tid;
      int row = c >> 2, kq = (c & 3) << 3;
      const float* ap = A + (long long)(m0 + row) * 256 + k0 + kq;
      float4v u0 = *(const float4v*)ap;
      float4v u1 = *(const float4v*)(ap + 4);
      if (doE) {
        float4v w1a = *(const float4v*)(aW1 + k0 + kq);
        float4v w1b = *(const float4v*)(aW1 + k0 + kq + 4);
        float4v w2a = *(const float4v*)(aW2 + k0 + kq);
        float4v w2b = *(const float4v*)(aW2 + k0 + kq + 4);
#pragma unroll
        for (int e = 0; e < 4; ++e) {
          s1q[q] += u0[e] * w1a[e] + u1[e] * w1b[e];
          s2q[q] += u0[e] * w2a[e] + u1[e] * w2b[e];
        }
      }
      uint4v uv;
      uv[0] = cvtpk_bf16(u0[0], u0[1]);
      uv[1] = cvtpk_bf16(u0[2], u0[3]);
      uv[2] = cvtpk_bf16(u1[0], u1[1]);
      uv[3] = cvtpk_bf16(u1[2], u1[3]);
      *(bf16x8*)(As + c * 8) = __builtin_bit_cast(bf16x8, uv);
    }
#pragma unroll
    for (int q = 0; q < 2; ++q) {
      int p = w * 2 + q;
      int c = p * 64 + lane;
      int row = c >> 2, kq = (c & 3) << 3;
      gload16(Bt + (long long)(n0 + row) * 256 + k0 + kq, Bs + p * 512);
    }
    __syncthreads();

    bf16x8 af[4], bfr[4];
#pragma unroll
    for (int i = 0; i < 4; ++i) {
      af[i]  = *(const bf16x8*)(As + (wr * 64 + i * 16 + lr) * 32 + 8 * g);
      bfr[i] = *(const bf16x8*)(Bs + (wc * 64 + i * 16 + lr) * 32 + 8 * g);
    }
#pragma unroll
    for (int i = 0; i < 4; ++i)
#pragma unroll
      for (int j = 0; j < 4; ++j)
        acc[i][j] = __builtin_amdgcn_mfma_f32_16x16x32_bf16(af[i], bfr[j], acc[i][j], 0, 0, 0);
  }

  if (doE) {
#pragma unroll
    for (int q = 0; q < 2; ++q) {
      float a1 = s1q[q], a2 = s2q[q];
      a1 += __shfl_xor(a1, 1, 64); a1 += __shfl_xor(a1, 2, 64);
      a2 += __shfl_xor(a2, 1, 64); a2 += __shfl_xor(a2, 2, 64);
      if ((tid & 3) == 0) {
        int row = m0 + q * 64 + (tid >> 2);
        e1[row] = a1; e2[row] = a2;
      }
    }
  }

  __syncthreads();
#pragma unroll
  for (int i = 0; i < 4; ++i) {
    int row_base = wr * 64 + i * 16 + 4 * g;
#pragma unroll
    for (int j = 0; j < 4; ++j) {
      int col = wc * 64 + j * 16 + lr;
#pragma unroll
      for (int r = 0; r < 4; ++r)
        T[col][row_base + r] = f2bf(acc[i][j][r]);
    }
  }
  __syncthreads();
  const int b = m0 >> 11, mloc = m0 & 2047;
  short* wb = Wht + (long long)b * 524288 + mloc;
#pragma unroll
  for (int p = 0; p < 8; ++p) {
    int c = (tid >> 4) + p * 16;
    int off = (tid & 15) * 8;
    bf16x8 v = *(const bf16x8*)(&T[c][off]);
    *(bf16x8*)(wb + (long long)(n0 + c) * 2048 + off) = v;
  }
}

// ------------- masked leakyrelu + row softmax -> attention f32 (R5-verbatim, BW-roofline) ------
__global__ __launch_bounds__(256) void attn_softmax_kernel(
    const int* __restrict__ adj, const float* __restrict__ e1,
    const float* __restrict__ e2, float* __restrict__ attn)
{
  const int i = blockIdx.x;
  const int b = blockIdx.y;
  const long long row = (long long)b * 2048 + i;
  const int tid = threadIdx.x;
  const int wid = tid >> 6, lane = tid & 63;
  const int j0 = tid * 8;

  const int*   arow = adj + row * 2048 + j0;
  const float  ei   = e1[row];
  const float* e2b  = e2 + b * 2048 + j0;

  int4v   a0 = *(const int4v*)(arow);
  int4v   a1 = *(const int4v*)(arow + 4);
  float4v f0 = *(const float4v*)(e2b);
  float4v f1 = *(const float4v*)(e2b + 4);

  float s[8];
#pragma unroll
  for (int k = 0; k < 8; ++k) {
    float x = ei + (k < 4 ? f0[k] : f1[k - 4]);
    float v = x > 0.f ? x : LRELU_ALPHA * x;
    int  ad = (k < 4 ? a0[k] : a1[k - 4]);
    s[k] = (ad > 0) ? v : NEG_INF;
  }
  float m = s[0];
#pragma unroll
  for (int k = 1; k < 8; ++k) m = fmaxf(m, s[k]);
#pragma unroll
  for (int off = 32; off > 0; off >>= 1) m = fmaxf(m, __shfl_xor(m, off, 64));

  __shared__ float wmax[4], wsum[4];
  if (lane == 0) wmax[wid] = m;
  __syncthreads();
  const float M = fmaxf(fmaxf(wmax[0], wmax[1]), fmaxf(wmax[2], wmax[3]));

  float p[8]; float t = 0.f;
#pragma unroll
  for (int k = 0; k < 8; ++k) { p[k] = __expf(s[k] - M); t += p[k]; }
#pragma unroll
  for (int off = 32; off > 0; off >>= 1) t += __shfl_xor(t, off, 64);
  if (lane == 0) wsum[wid] = t;
  __syncthreads();
  const float S = wsum[0] + wsum[1] + wsum[2] + wsum[3];
  const float r = 1.0f / S;

  float4v o0, o1;
#pragma unroll
  for (int k = 0; k < 4; ++k) { o0[k] = p[k] * r; o1[k] = p[k + 4] * r; }
  float* op = attn + row * 2048 + j0;
  *(float4v*)op       = o0;
  *(float4v*)(op + 4) = o1;
}

// ------------- h_prime GEMM (R5-VERBATIM, the measured-fast variant):
// C(2048x256,f32,ELU) = A(2048x2048,f32) @ Bt(256x2048,bf16)^T. M-tile 32, full N=256,
// BK=64, grid 512 flat (bz=bid&7 XCD-pinned). A reg-staged f32->bf16 (swizzled ds_write),
// Bs via global_load_lds (pre-swizzled source). One STAGE+barrier pair per 64-K step. ----
__global__ __launch_bounds__(256, 4) void gemm_attn_kernel(
    const float* __restrict__ A, const short* __restrict__ Bt,
    float* __restrict__ C)
{
  __shared__ short As[32 * 64];     // 4 KB
  __shared__ short Bs[256 * 64];    // 32 KB
  const int bid = blockIdx.x;
  const int bz = bid & 7;
  const int m0 = (bid >> 3) << 5;   // 64 m-tiles of 32 rows per batch
  A  += (long long)bz * 4194304;    // 2048*2048
  Bt += (long long)bz * 524288;     // 256*2048
  C  += (long long)bz * 524288;     // 2048*256
  const int tid = threadIdx.x;
  const int w = tid >> 6, lane = tid & 63;
  const int g = lane >> 4, lr = lane & 15;

  f32x4 acc[2][4] = {};

  // A-stage: thread handles (row ar, 16B-chunk ac8): 32 rows x 8 chunks = 256
  const int ar = tid >> 3, ac8 = tid & 7;
  short* as_wr = As + ar * 64 + ((ac8 ^ (ar & 7)) << 3);
  const float* a_rd_base = A + (long long)(m0 + ar) * 2048 + ac8 * 8;

  // B-stage: per wave-issue p: lane covers col = p*8 + (lane>>3), fetches global
  // chunk c = (lane&7) ^ ((lane>>3)&7) into linear LDS slot (lane&7)  [involution]
  const int bcol_off = lane >> 3;
  const int bchunk   = (lane & 7) ^ ((lane >> 3) & 7);

  for (int k0 = 0; k0 < 2048; k0 += 64) {
    __syncthreads();
    // stage A: 32x64 f32 -> bf16, swizzled ds_write_b128
    {
      const float* ap = a_rd_base + k0;
      float4v u0 = *(const float4v*)ap;
      float4v u1 = *(const float4v*)(ap + 4);
      short os[8] __attribute__((aligned(16)));
#pragma unroll
      for (int k = 0; k < 8; ++k) os[k] = f2bf(k < 4 ? u0[k] : u1[k - 4]);
      *(bf16x8*)as_wr = *(const bf16x8*)os;
    }
    // stage B: 256x64 bf16, 32 wave-issues of 1 KB
#pragma unroll
    for (int q = 0; q < 8; ++q) {
      int p = w * 8 + q;
      int col = p * 8 + bcol_off;
      gload16(Bt + (long long)col * 2048 + k0 + bchunk * 8, Bs + p * 512);
    }
    __syncthreads();

    bf16x8 af[2][2], bfr[4][2];
#pragma unroll
    for (int i = 0; i < 2; ++i) {
      int row = i * 16 + lr;
#pragma unroll
      for (int s = 0; s < 2; ++s)
        af[i][s] = *(const bf16x8*)(As + row * 64 + (((s * 4 + g) ^ (row & 7)) << 3));
    }
#pragma unroll
    for (int j = 0; j < 4; ++j) {
      int col = w * 64 + j * 16 + lr;
#pragma unroll
      for (int s = 0; s < 2; ++s)
        bfr[j][s] = *(const bf16x8*)(Bs + col * 64 + (((s * 4 + g) ^ (col & 7)) << 3));
    }
#pragma unroll
    for (int s = 0; s < 2; ++s)
#pragma unroll
      for (int i = 0; i < 2; ++i)
#pragma unroll
        for (int j = 0; j < 4; ++j)
          acc[i][j] = __builtin_amdgcn_mfma_f32_16x16x32_bf16(af[i][s], bfr[j][s], acc[i][j], 0, 0, 0);
  }

  // C/D: col=lane&15, row=(lane>>4)*4+reg  [m89]
#pragma unroll
  for (int i = 0; i < 2; ++i) {
    int row_base = m0 + i * 16 + 4 * g;
#pragma unroll
    for (int j = 0; j < 4; ++j) {
      int col = w * 64 + j * 16 + lr;
#pragma unroll
      for (int r = 0; r < 4; ++r) {
        float v = acc[i][j][r];
        v = (v > 0.f) ? v : (__expf(v) - 1.f);   // ELU
        C[(long long)(row_base + r) * 256 + col] = v;
      }
    }
  }
}

extern "C" void kernel_launch(void* const* d_in, const int* in_sizes, int n_in,
                              void* d_out, int out_size, void* d_ws, size_t ws_size,
                              hipStream_t stream)
{
  const float* h   = (const float*)d_in[0];   // (8,2048,256) f32
  const int*   adj = (const int*)d_in[1];     // (8,2048,2048) int32
  const float* W   = (const float*)d_in[2];   // (256,256) f32
  const float* a   = (const float*)d_in[3];   // (512,1) f32

  float* hp_out   = (float*)d_out;            // elu(h_prime): 4,194,304 f32
  float* attn_out = hp_out + 4194304LL;       // attention: 33,554,432 f32

  // workspace: ~8.7 MB
  short* W_t  = (short*)d_ws;                 // 65,536 shorts
  short* Wh_t = W_t + 65536;                  // 8 x (256x2048) shorts (8.39 MB)
  float* e1   = (float*)(Wh_t + 4194304);     // 16384
  float* e2   = e1 + 16384;
  float* aW1  = e2 + 16384;                   // 256
  float* aW2  = aW1 + 256;                    // 256

  // 1) W^T (bf16) + aW1/aW2 = W @ a1/a2
  prep_kernel<<<17, 256, 0, stream>>>(W, a, W_t, aW1, aW2);
  // 2) Wh_t = (cast(h) @ W)^T with fused e1/e2 = h @ aW
  gemm_h_kernel<<<dim3(128, 2), 256, 0, stream>>>(h, W_t, Wh_t, aW1, aW2, e1, e2);
  // 3) masked softmax -> final f32 attention (BW-roofline, fire-and-forget stores)
  attn_softmax_kernel<<<dim3(2048, 8), 256, 0, stream>>>(adj, e1, e2, attn_out);
  // 4) h_prime = attention @ Wh with fused ELU (R5-verbatim gemm_attn)
  gemm_attn_kernel<<<512, 256, 0, stream>>>(attn_out, Wh_t, hp_out);
}

// Round 21
// 108.761 us; speedup vs baseline: 1.1207x; 1.0476x over previous
//
#include <hip/hip_runtime.h>
#include <hip/hip_bf16.h>
#include <stdint.h>

#define NEG_INF -9.0e15f
#define LRELU_ALPHA 0.2f
#define LOG2E 1.442695040888963f

using bf16x8  = __attribute__((ext_vector_type(8))) short;
using f32x4   = __attribute__((ext_vector_type(4))) float;
using short4v = __attribute__((ext_vector_type(4))) short;
using int4v   = __attribute__((ext_vector_type(4))) int;
using float4v = __attribute__((ext_vector_type(4))) float;
using uint2v  = __attribute__((ext_vector_type(2))) unsigned;
using uint4v  = __attribute__((ext_vector_type(4))) unsigned;

static __device__ __forceinline__ short f2bf(float f) {
  unsigned u = __builtin_bit_cast(unsigned, f);
  u = u + 0x7FFFu + ((u >> 16) & 1u);   // RNE
  return (short)(u >> 16);
}
static __device__ __forceinline__ unsigned cvtpk_bf16(float lo, float hi) {
  unsigned r;
  asm volatile("v_cvt_pk_bf16_f32 %0, %1, %2" : "=v"(r) : "v"(lo), "v"(hi));
  return r;
}
static __device__ __forceinline__ void gload16(const void* g, void* l) {
  __builtin_amdgcn_global_load_lds((const __attribute__((address_space(1))) void*)g,
                                   (__attribute__((address_space(3))) void*)l, 16, 0, 0);
}

// ---------- prep: blocks 0..15 = W(f32)->W^T(bf16); block 16 = aW1/aW2 = W @ a1/a2 ----------
__global__ __launch_bounds__(256) void prep_kernel(
    const float* __restrict__ W, const float* __restrict__ a,
    short* __restrict__ W_t, float* __restrict__ aW1, float* __restrict__ aW2)
{
  const int bid = blockIdx.x;
  const int tid = threadIdx.x;
  if (bid < 16) {
    __shared__ float t[64][65];
    const int m0 = (bid & 3) * 64, n0 = (bid >> 2) * 64;
    const int rr = tid >> 3, cc = (tid & 7) * 8;
#pragma unroll
    for (int p = 0; p < 2; ++p) {
      int row = rr + p * 32;
      const float* sp = W + (m0 + row) * 256 + n0 + cc;
      float4v v0 = *(const float4v*)sp;
      float4v v1 = *(const float4v*)(sp + 4);
#pragma unroll
      for (int j = 0; j < 4; ++j) { t[row][cc + j] = v0[j]; t[row][cc + 4 + j] = v1[j]; }
    }
    __syncthreads();
#pragma unroll
    for (int p = 0; p < 2; ++p) {
      int orow = rr + p * 32;
      short vv[8] __attribute__((aligned(16)));
#pragma unroll
      for (int j = 0; j < 8; ++j) vv[j] = f2bf(t[cc + j][orow]);
      short* dp = W_t + (n0 + orow) * 256 + m0 + cc;
      *(int4v*)dp = *(const int4v*)vv;
    }
  } else {
    const int r8 = tid >> 3, o4 = (tid & 7) * 4;
    float s1[8] = {}, s2[8] = {};
#pragma unroll
    for (int rp = 0; rp < 8; ++rp) {
      int row = r8 + rp * 32;
#pragma unroll
      for (int k = 0; k < 8; ++k) {
        int o = o4 + k * 32;
        float4v wv = *(const float4v*)(W + row * 256 + o);
        float4v a1 = *(const float4v*)(a + o);
        float4v a2 = *(const float4v*)(a + 256 + o);
#pragma unroll
        for (int e = 0; e < 4; ++e) { s1[rp] += wv[e] * a1[e]; s2[rp] += wv[e] * a2[e]; }
      }
    }
#pragma unroll
    for (int rp = 0; rp < 8; ++rp) {
#pragma unroll
      for (int off = 4; off > 0; off >>= 1) {
        s1[rp] += __shfl_xor(s1[rp], off, 64);
        s2[rp] += __shfl_xor(s2[rp], off, 64);
      }
      if ((tid & 7) == 0) { aW1[r8 + rp * 32] = s1[rp]; aW2[r8 + rp * 32] = s2[rp]; }
    }
  }
}

// ---------- Wh_t = (cast(h) @ W)^T per batch, with FUSED e1/e2 = h @ aW (y==0 blocks) ----------
__global__ __launch_bounds__(256) void gemm_h_kernel(
    const float* __restrict__ A, const short* __restrict__ Bt,
    short* __restrict__ Wht, const float* __restrict__ aW1,
    const float* __restrict__ aW2, float* __restrict__ e1, float* __restrict__ e2)
{
  __shared__ short As[128 * 32];
  __shared__ short Bs[128 * 32];
  __shared__ short T[128][136];
  const int m0 = blockIdx.x * 128, n0 = blockIdx.y * 128;
  const int tid = threadIdx.x;
  const int w = tid >> 6, lane = tid & 63;
  const int wr = w >> 1, wc = w & 1;
  const int g = lane >> 4, lr = lane & 15;
  const bool doE = (blockIdx.y == 0);

  f32x4 acc[4][4] = {};
  float s1q[2] = {0.f, 0.f}, s2q[2] = {0.f, 0.f};

  for (int k0 = 0; k0 < 256; k0 += 32) {
    __syncthreads();
#pragma unroll
    for (int q = 0; q < 2; ++q) {
      int c = q * 256 + tid;
      int row = c >> 2, kq = (c & 3) << 3;
      const float* ap = A + (long long)(m0 + row) * 256 + k0 + kq;
      float4v u0 = *(const float4v*)ap;
      float4v u1 = *(const float4v*)(ap + 4);
      if (doE) {
        float4v w1a = *(const float4v*)(aW1 + k0 + kq);
        float4v w1b = *(const float4v*)(aW1 + k0 + kq + 4);
        float4v w2a = *(const float4v*)(aW2 + k0 + kq);
        float4v w2b = *(const float4v*)(aW2 + k0 + kq + 4);
#pragma unroll
        for (int e = 0; e < 4; ++e) {
          s1q[q] += u0[e] * w1a[e] + u1[e] * w1b[e];
          s2q[q] += u0[e] * w2a[e] + u1[e] * w2b[e];
        }
      }
      uint4v uv;
      uv[0] = cvtpk_bf16(u0[0], u0[1]);
      uv[1] = cvtpk_bf16(u0[2], u0[3]);
      uv[2] = cvtpk_bf16(u1[0], u1[1]);
      uv[3] = cvtpk_bf16(u1[2], u1[3]);
      *(bf16x8*)(As + c * 8) = __builtin_bit_cast(bf16x8, uv);
    }
#pragma unroll
    for (int q = 0; q < 2; ++q) {
      int p = w * 2 + q;
      int c = p * 64 + lane;
      int row = c >> 2, kq = (c & 3) << 3;
      gload16(Bt + (long long)(n0 + row) * 256 + k0 + kq, Bs + p * 512);
    }
    __syncthreads();

    bf16x8 af[4], bfr[4];
#pragma unroll
    for (int i = 0; i < 4; ++i) {
      af[i]  = *(const bf16x8*)(As + (wr * 64 + i * 16 + lr) * 32 + 8 * g);
      bfr[i] = *(const bf16x8*)(Bs + (wc * 64 + i * 16 + lr) * 32 + 8 * g);
    }
#pragma unroll
    for (int i = 0; i < 4; ++i)
#pragma unroll
      for (int j = 0; j < 4; ++j)
        acc[i][j] = __builtin_amdgcn_mfma_f32_16x16x32_bf16(af[i], bfr[j], acc[i][j], 0, 0, 0);
  }

  if (doE) {
#pragma unroll
    for (int q = 0; q < 2; ++q) {
      float a1 = s1q[q], a2 = s2q[q];
      a1 += __shfl_xor(a1, 1, 64); a1 += __shfl_xor(a1, 2, 64);
      a2 += __shfl_xor(a2, 1, 64); a2 += __shfl_xor(a2, 2, 64);
      if ((tid & 3) == 0) {
        int row = m0 + q * 64 + (tid >> 2);
        e1[row] = a1; e2[row] = a2;
      }
    }
  }

  __syncthreads();
#pragma unroll
  for (int i = 0; i < 4; ++i) {
    int row_base = wr * 64 + i * 16 + 4 * g;
#pragma unroll
    for (int j = 0; j < 4; ++j) {
      int col = wc * 64 + j * 16 + lr;
#pragma unroll
      for (int r = 0; r < 4; ++r)
        T[col][row_base + r] = f2bf(acc[i][j][r]);
    }
  }
  __syncthreads();
  const int b = m0 >> 11, mloc = m0 & 2047;
  short* wb = Wht + (long long)b * 524288 + mloc;
#pragma unroll
  for (int p = 0; p < 8; ++p) {
    int c = (tid >> 4) + p * 16;
    int off = (tid & 15) * 8;
    bf16x8 v = *(const bf16x8*)(&T[c][off]);
    *(bf16x8*)(wb + (long long)(n0 + c) * 2048 + off) = v;
  }
}

// ---------- pass 1: adj -> bitmask + per-row softmax consts (R12-verbatim, high-TLP) ----------
__global__ __launch_bounds__(256) void pack_stats_kernel(
    const int* __restrict__ adj, const float* __restrict__ e1,
    const float* __restrict__ e2, unsigned char* __restrict__ mask,
    float* __restrict__ Lr, float* __restrict__ Dr)
{
  const int i = blockIdx.x;
  const int b = blockIdx.y;
  const long long row = (long long)b * 2048 + i;
  const int tid = threadIdx.x;
  const int wid = tid >> 6, lane = tid & 63;
  const int j0 = tid * 8;

  const int*   arow = adj + row * 2048 + j0;
  const float  ei   = e1[row];
  const float* e2b  = e2 + b * 2048 + j0;

  int4v   a0 = *(const int4v*)(arow);
  int4v   a1 = *(const int4v*)(arow + 4);
  float4v f0 = *(const float4v*)(e2b);
  float4v f1 = *(const float4v*)(e2b + 4);

  float s[8]; unsigned byte = 0u;
#pragma unroll
  for (int k = 0; k < 8; ++k) {
    float x = ei + (k < 4 ? f0[k] : f1[k - 4]);
    float v = fmaxf(x, LRELU_ALPHA * x);
    int  ad = (k < 4 ? a0[k] : a1[k - 4]);
    if (ad > 0) { s[k] = v; byte |= (1u << k); } else s[k] = NEG_INF;
  }
  float m = s[0];
#pragma unroll
  for (int k = 1; k < 8; ++k) m = fmaxf(m, s[k]);
#pragma unroll
  for (int off = 32; off > 0; off >>= 1) m = fmaxf(m, __shfl_xor(m, off, 64));

  __shared__ float wmax[4], wsum[4];
  if (lane == 0) wmax[wid] = m;
  __syncthreads();
  const float M = fmaxf(fmaxf(wmax[0], wmax[1]), fmaxf(wmax[2], wmax[3]));
  const bool empty = (M == NEG_INF);

  mask[row * 256 + tid] = empty ? (unsigned char)0xFF : (unsigned char)byte;

  float t = 0.f;
#pragma unroll
  for (int k = 0; k < 8; ++k) t += __expf(s[k] - M);
#pragma unroll
  for (int off = 32; off > 0; off >>= 1) t += __shfl_xor(t, off, 64);
  if (lane == 0) wsum[wid] = t;
  __syncthreads();
  if (tid == 0) {
    const float S = wsum[0] + wsum[1] + wsum[2] + wsum[3];
    Lr[row] = empty ? 0.0f : LOG2E;
    Dr[row] = empty ? -11.0f : (-M * LOG2E - __log2f(S));
  }
}

// ---------- pass 2: R12-exact pipelined pv + T5 setprio around the MFMA cluster ----------
__global__ __launch_bounds__(256, 3) void pv_kernel(
    const unsigned char* __restrict__ mask, const float* __restrict__ e1,
    const float* __restrict__ e2, const float* __restrict__ Lr,
    const float* __restrict__ Dr, const short* __restrict__ Bt,
    float* __restrict__ attnw, float* __restrict__ C)
{
  __shared__ short As0[32 * 32],  As1[32 * 32];     // 2 x 2 KB
  __shared__ short Bs0[256 * 32], Bs1[256 * 32];    // 2 x 16 KB
  __shared__ float e2s[2048];                       // 8 KB
  __shared__ unsigned char msk[32 * 256];           // 8 KB
  const int bid = blockIdx.x;
  const int bz  = bid & 7;          // XCD-pinned batch
  const int M0  = (bid >> 3) << 5;
  const int tid = threadIdx.x;
  const int w = tid >> 6, lane = tid & 63;
  const int g = lane >> 4, lr = lane & 15;

  const long long rb = (long long)bz * 2048;
  Bt    += (long long)bz * 524288;
  attnw += (long long)bz * 4194304;
  C     += (long long)bz * 524288;

  const int pr = tid >> 3, k4 = (tid & 7) << 2;
  const int prow = M0 + pr;
  const float E1p = e1[rb + prow];
  const float Lp  = Lr[rb + prow];
  const float Dp  = Dr[rb + prow];
  float* arow = attnw + (long long)prow * 2048;
  const int kc = k4 >> 3;
  const int as_off = pr * 32 + ((kc ^ ((pr >> 1) & 3)) << 3) + (k4 & 7);

  const int bcol_off = lane >> 2;
  const int bchunk   = (lane & 3) ^ ((lane >> 3) & 3);

  // ---- prologue: hoist e2 row (8 KB) + 32 mask rows (8 KB); 1024 B per issue ----
  {
    const float* e2g = e2 + rb;
    const unsigned char* mg = mask + (rb + M0) * 256;
#pragma unroll
    for (int q = 0; q < 2; ++q) {
      int p = w * 2 + q;                                // 0..7, wave-uniform
      gload16(e2g + p * 256 + lane * 4, (char*)e2s + p * 1024);
      gload16(mg  + p * 1024 + lane * 16, (char*)msk + p * 1024);
    }
  }

  f32x4 acc[2][4] = {};

  auto STAGE = [&](short* BsD, short* AsD, int k0) {
#pragma unroll
    for (int q = 0; q < 4; ++q) {
      int pp = w * 4 + q;
      int col = pp * 16 + bcol_off;
      gload16(Bt + (long long)col * 2048 + k0 + bchunk * 8, BsD + pp * 512);
    }
    const int kk = k0 + k4;
    const unsigned by = (unsigned)(msk[pr * 256 + (kk >> 3)] >> (k4 & 7)) & 0xFu;
    float4v ev = *(const float4v*)(e2s + kk);
    float p4[4];
#pragma unroll
    for (int e = 0; e < 4; ++e) {
      float x = E1p + ev[e];
      float v = fmaxf(x, LRELU_ALPHA * x);
      float P = __builtin_amdgcn_exp2f(fmaf(v, Lp, Dp));
      p4[e] = ((by >> e) & 1u) ? P : 0.0f;
    }
    float4v o;
#pragma unroll
    for (int e = 0; e < 4; ++e) o[e] = p4[e];
    *(float4v*)(arow + kk) = o;                    // attention (f32), once
    uint2v uv;
    uv[0] = cvtpk_bf16(p4[0], p4[1]);
    uv[1] = cvtpk_bf16(p4[2], p4[3]);
    *(uint2v*)(AsD + as_off) = uv;
  };

  auto COMPUTE = [&](const short* BsD, const short* AsD) {
    bf16x8 af[2], bfr[4];
#pragma unroll
    for (int i = 0; i < 2; ++i) {
      int row = i * 16 + lr;
      af[i] = *(const bf16x8*)(AsD + row * 32 + ((g ^ ((row >> 1) & 3)) << 3));
    }
#pragma unroll
    for (int j = 0; j < 4; ++j) {
      int col = w * 64 + j * 16 + lr;
      bfr[j] = *(const bf16x8*)(BsD + col * 32 + ((g ^ ((col >> 1) & 3)) << 3));
    }
    __builtin_amdgcn_s_setprio(1);                 // T5: favor MFMA-phase waves
#pragma unroll
    for (int i = 0; i < 2; ++i)
#pragma unroll
      for (int j = 0; j < 4; ++j)
        acc[i][j] = __builtin_amdgcn_mfma_f32_16x16x32_bf16(af[i], bfr[j], acc[i][j], 0, 0, 0);
    __builtin_amdgcn_s_setprio(0);
  };

  __syncthreads();                 // e2s/msk staged (barrier drains vmcnt)
  STAGE(Bs0, As0, 0);
  __syncthreads();
  for (int t = 0; t < 64; t += 2) {
    STAGE(Bs1, As1, (t + 1) * 32);
    COMPUTE(Bs0, As0);
    __syncthreads();
    if (t + 2 < 64) STAGE(Bs0, As0, (t + 2) * 32);
    COMPUTE(Bs1, As1);
    __syncthreads();
  }

  // C/D: col=lane&15, row=(lane>>4)*4+reg  [m89]
#pragma unroll
  for (int i = 0; i < 2; ++i) {
    int row_base = M0 + i * 16 + 4 * g;
#pragma unroll
    for (int j = 0; j < 4; ++j) {
      int col = w * 64 + j * 16 + lr;
#pragma unroll
      for (int r = 0; r < 4; ++r) {
        float v = acc[i][j][r];
        v = (v > 0.f) ? v : (__expf(v) - 1.f);   // ELU
        C[(long long)(row_base + r) * 256 + col] = v;
      }
    }
  }
}

extern "C" void kernel_launch(void* const* d_in, const int* in_sizes, int n_in,
                              void* d_out, int out_size, void* d_ws, size_t ws_size,
                              hipStream_t stream)
{
  const float* h   = (const float*)d_in[0];   // (8,2048,256) f32
  const int*   adj = (const int*)d_in[1];     // (8,2048,2048) int32
  const float* W   = (const float*)d_in[2];   // (256,256) f32
  const float* a   = (const float*)d_in[3];   // (512,1) f32

  float* hp_out   = (float*)d_out;            // elu(h_prime): 4,194,304 f32
  float* attn_out = hp_out + 4194304LL;       // attention: 33,554,432 f32

  // workspace: ~13.0 MB (R12-proven layout)
  unsigned char* mask = (unsigned char*)d_ws; // 4.19 MB
  short* W_t  = (short*)(mask + 4194304);     // 256x256 bf16
  short* Wh_t = W_t + 65536;                  // 8 x (256x2048) bf16
  float* e1   = (float*)(Wh_t + 4194304);     // 16384
  float* e2   = e1 + 16384;
  float* Lr   = e2 + 16384;
  float* Dr   = Lr + 16384;
  float* aW1  = Dr + 16384;                   // 256
  float* aW2  = aW1 + 256;                    // 256

  // 1) W^T (bf16) + aW1/aW2 = W @ a1/a2
  prep_kernel<<<17, 256, 0, stream>>>(W, a, W_t, aW1, aW2);
  // 2) Wh_t = (cast(h) @ W)^T with fused e1/e2 = h @ aW
  gemm_h_kernel<<<dim3(128, 2), 256, 0, stream>>>(h, W_t, Wh_t, aW1, aW2, e1, e2);
  // 3) adj -> bitmask + per-row (L,D)  (high-TLP, coalesced)
  pack_stats_kernel<<<dim3(2048, 8), 256, 0, stream>>>(adj, e1, e2, mask, Lr, Dr);
  // 4) pipelined pv (R12-exact + T5 setprio): attention write + P @ Wh_t + ELU
  pv_kernel<<<512, 256, 0, stream>>>(mask, e1, e2, Lr, Dr, Wh_t, attn_out, hp_out);
}

// Round 22
// 108.677 us; speedup vs baseline: 1.1216x; 1.0008x over previous
//
#include <hip/hip_runtime.h>
#include <hip/hip_bf16.h>
#include <stdint.h>

#define NEG_INF -9.0e15f
#define LRELU_ALPHA 0.2f
#define LOG2E 1.442695040888963f

using bf16x8  = __attribute__((ext_vector_type(8))) short;
using f32x4   = __attribute__((ext_vector_type(4))) float;
using short4v = __attribute__((ext_vector_type(4))) short;
using int4v   = __attribute__((ext_vector_type(4))) int;
using float4v = __attribute__((ext_vector_type(4))) float;
using uint2v  = __attribute__((ext_vector_type(2))) unsigned;
using uint4v  = __attribute__((ext_vector_type(4))) unsigned;

static __device__ __forceinline__ short f2bf(float f) {
  unsigned u = __builtin_bit_cast(unsigned, f);
  u = u + 0x7FFFu + ((u >> 16) & 1u);   // RNE
  return (short)(u >> 16);
}
static __device__ __forceinline__ unsigned cvtpk_bf16(float lo, float hi) {
  unsigned r;
  asm volatile("v_cvt_pk_bf16_f32 %0, %1, %2" : "=v"(r) : "v"(lo), "v"(hi));
  return r;
}
static __device__ __forceinline__ void gload16(const void* g, void* l) {
  __builtin_amdgcn_global_load_lds((const __attribute__((address_space(1))) void*)g,
                                   (__attribute__((address_space(3))) void*)l, 16, 0, 0);
}

// ---------- prep: blocks 0..15 = W(f32)->W^T(bf16); block 16 = aW1/aW2 = W @ a1/a2 ----------
__global__ __launch_bounds__(256) void prep_kernel(
    const float* __restrict__ W, const float* __restrict__ a,
    short* __restrict__ W_t, float* __restrict__ aW1, float* __restrict__ aW2)
{
  const int bid = blockIdx.x;
  const int tid = threadIdx.x;
  if (bid < 16) {
    __shared__ float t[64][65];
    const int m0 = (bid & 3) * 64, n0 = (bid >> 2) * 64;
    const int rr = tid >> 3, cc = (tid & 7) * 8;
#pragma unroll
    for (int p = 0; p < 2; ++p) {
      int row = rr + p * 32;
      const float* sp = W + (m0 + row) * 256 + n0 + cc;
      float4v v0 = *(const float4v*)sp;
      float4v v1 = *(const float4v*)(sp + 4);
#pragma unroll
      for (int j = 0; j < 4; ++j) { t[row][cc + j] = v0[j]; t[row][cc + 4 + j] = v1[j]; }
    }
    __syncthreads();
#pragma unroll
    for (int p = 0; p < 2; ++p) {
      int orow = rr + p * 32;
      short vv[8] __attribute__((aligned(16)));
#pragma unroll
      for (int j = 0; j < 8; ++j) vv[j] = f2bf(t[cc + j][orow]);
      short* dp = W_t + (n0 + orow) * 256 + m0 + cc;
      *(int4v*)dp = *(const int4v*)vv;
    }
  } else {
    const int r8 = tid >> 3, o4 = (tid & 7) * 4;
    float s1[8] = {}, s2[8] = {};
#pragma unroll
    for (int rp = 0; rp < 8; ++rp) {
      int row = r8 + rp * 32;
#pragma unroll
      for (int k = 0; k < 8; ++k) {
        int o = o4 + k * 32;
        float4v wv = *(const float4v*)(W + row * 256 + o);
        float4v a1 = *(const float4v*)(a + o);
        float4v a2 = *(const float4v*)(a + 256 + o);
#pragma unroll
        for (int e = 0; e < 4; ++e) { s1[rp] += wv[e] * a1[e]; s2[rp] += wv[e] * a2[e]; }
      }
    }
#pragma unroll
    for (int rp = 0; rp < 8; ++rp) {
#pragma unroll
      for (int off = 4; off > 0; off >>= 1) {
        s1[rp] += __shfl_xor(s1[rp], off, 64);
        s2[rp] += __shfl_xor(s2[rp], off, 64);
      }
      if ((tid & 7) == 0) { aW1[r8 + rp * 32] = s1[rp]; aW2[r8 + rp * 32] = s2[rp]; }
    }
  }
}

// ---------- Wh_t = (cast(h) @ W)^T per batch, with FUSED e1/e2 = h @ aW (y==0 blocks) ----------
__global__ __launch_bounds__(256) void gemm_h_kernel(
    const float* __restrict__ A, const short* __restrict__ Bt,
    short* __restrict__ Wht, const float* __restrict__ aW1,
    const float* __restrict__ aW2, float* __restrict__ e1, float* __restrict__ e2)
{
  __shared__ short As[128 * 32];
  __shared__ short Bs[128 * 32];
  __shared__ short T[128][136];
  const int m0 = blockIdx.x * 128, n0 = blockIdx.y * 128;
  const int tid = threadIdx.x;
  const int w = tid >> 6, lane = tid & 63;
  const int wr = w >> 1, wc = w & 1;
  const int g = lane >> 4, lr = lane & 15;
  const bool doE = (blockIdx.y == 0);

  f32x4 acc[4][4] = {};
  float s1q[2] = {0.f, 0.f}, s2q[2] = {0.f, 0.f};

  for (int k0 = 0; k0 < 256; k0 += 32) {
    __syncthreads();
#pragma unroll
    for (int q = 0; q < 2; ++q) {
      int c = q * 256 + tid;
      int row = c >> 2, kq = (c & 3) << 3;
      const float* ap = A + (long long)(m0 + row) * 256 + k0 + kq;
      float4v u0 = *(const float4v*)ap;
      float4v u1 = *(const float4v*)(ap + 4);
      if (doE) {
        float4v w1a = *(const float4v*)(aW1 + k0 + kq);
        float4v w1b = *(const float4v*)(aW1 + k0 + kq + 4);
        float4v w2a = *(const float4v*)(aW2 + k0 + kq);
        float4v w2b = *(const float4v*)(aW2 + k0 + kq + 4);
#pragma unroll
        for (int e = 0; e < 4; ++e) {
          s1q[q] += u0[e] * w1a[e] + u1[e] * w1b[e];
          s2q[q] += u0[e] * w2a[e] + u1[e] * w2b[e];
        }
      }
      uint4v uv;
      uv[0] = cvtpk_bf16(u0[0], u0[1]);
      uv[1] = cvtpk_bf16(u0[2], u0[3]);
      uv[2] = cvtpk_bf16(u1[0], u1[1]);
      uv[3] = cvtpk_bf16(u1[2], u1[3]);
      *(bf16x8*)(As + c * 8) = __builtin_bit_cast(bf16x8, uv);
    }
#pragma unroll
    for (int q = 0; q < 2; ++q) {
      int p = w * 2 + q;
      int c = p * 64 + lane;
      int row = c >> 2, kq = (c & 3) << 3;
      gload16(Bt + (long long)(n0 + row) * 256 + k0 + kq, Bs + p * 512);
    }
    __syncthreads();

    bf16x8 af[4], bfr[4];
#pragma unroll
    for (int i = 0; i < 4; ++i) {
      af[i]  = *(const bf16x8*)(As + (wr * 64 + i * 16 + lr) * 32 + 8 * g);
      bfr[i] = *(const bf16x8*)(Bs + (wc * 64 + i * 16 + lr) * 32 + 8 * g);
    }
#pragma unroll
    for (int i = 0; i < 4; ++i)
#pragma unroll
      for (int j = 0; j < 4; ++j)
        acc[i][j] = __builtin_amdgcn_mfma_f32_16x16x32_bf16(af[i], bfr[j], acc[i][j], 0, 0, 0);
  }

  if (doE) {
#pragma unroll
    for (int q = 0; q < 2; ++q) {
      float a1 = s1q[q], a2 = s2q[q];
      a1 += __shfl_xor(a1, 1, 64); a1 += __shfl_xor(a1, 2, 64);
      a2 += __shfl_xor(a2, 1, 64); a2 += __shfl_xor(a2, 2, 64);
      if ((tid & 3) == 0) {
        int row = m0 + q * 64 + (tid >> 2);
        e1[row] = a1; e2[row] = a2;
      }
    }
  }

  __syncthreads();
#pragma unroll
  for (int i = 0; i < 4; ++i) {
    int row_base = wr * 64 + i * 16 + 4 * g;
#pragma unroll
    for (int j = 0; j < 4; ++j) {
      int col = wc * 64 + j * 16 + lr;
#pragma unroll
      for (int r = 0; r < 4; ++r)
        T[col][row_base + r] = f2bf(acc[i][j][r]);
    }
  }
  __syncthreads();
  const int b = m0 >> 11, mloc = m0 & 2047;
  short* wb = Wht + (long long)b * 524288 + mloc;
#pragma unroll
  for (int p = 0; p < 8; ++p) {
    int c = (tid >> 4) + p * 16;
    int off = (tid & 15) * 8;
    bf16x8 v = *(const bf16x8*)(&T[c][off]);
    *(bf16x8*)(wb + (long long)(n0 + c) * 2048 + off) = v;
  }
}

// ---------- pass 1: adj -> bitmask + per-row softmax consts (R12-verbatim, high-TLP) ----------
__global__ __launch_bounds__(256) void pack_stats_kernel(
    const int* __restrict__ adj, const float* __restrict__ e1,
    const float* __restrict__ e2, unsigned char* __restrict__ mask,
    float* __restrict__ Lr, float* __restrict__ Dr)
{
  const int i = blockIdx.x;
  const int b = blockIdx.y;
  const long long row = (long long)b * 2048 + i;
  const int tid = threadIdx.x;
  const int wid = tid >> 6, lane = tid & 63;
  const int j0 = tid * 8;

  const int*   arow = adj + row * 2048 + j0;
  const float  ei   = e1[row];
  const float* e2b  = e2 + b * 2048 + j0;

  int4v   a0 = *(const int4v*)(arow);
  int4v   a1 = *(const int4v*)(arow + 4);
  float4v f0 = *(const float4v*)(e2b);
  float4v f1 = *(const float4v*)(e2b + 4);

  float s[8]; unsigned byte = 0u;
#pragma unroll
  for (int k = 0; k < 8; ++k) {
    float x = ei + (k < 4 ? f0[k] : f1[k - 4]);
    float v = fmaxf(x, LRELU_ALPHA * x);
    int  ad = (k < 4 ? a0[k] : a1[k - 4]);
    if (ad > 0) { s[k] = v; byte |= (1u << k); } else s[k] = NEG_INF;
  }
  float m = s[0];
#pragma unroll
  for (int k = 1; k < 8; ++k) m = fmaxf(m, s[k]);
#pragma unroll
  for (int off = 32; off > 0; off >>= 1) m = fmaxf(m, __shfl_xor(m, off, 64));

  __shared__ float wmax[4], wsum[4];
  if (lane == 0) wmax[wid] = m;
  __syncthreads();
  const float M = fmaxf(fmaxf(wmax[0], wmax[1]), fmaxf(wmax[2], wmax[3]));
  const bool empty = (M == NEG_INF);

  mask[row * 256 + tid] = empty ? (unsigned char)0xFF : (unsigned char)byte;

  float t = 0.f;
#pragma unroll
  for (int k = 0; k < 8; ++k) t += __expf(s[k] - M);
#pragma unroll
  for (int off = 32; off > 0; off >>= 1) t += __shfl_xor(t, off, 64);
  if (lane == 0) wsum[wid] = t;
  __syncthreads();
  if (tid == 0) {
    const float S = wsum[0] + wsum[1] + wsum[2] + wsum[3];
    Lr[row] = empty ? 0.0f : LOG2E;
    Dr[row] = empty ? -11.0f : (-M * LOG2E - __log2f(S));
  }
}

// ---------- pass 2: R12-exact pipelined pv + T5 setprio around the MFMA cluster ----------
__global__ __launch_bounds__(256, 3) void pv_kernel(
    const unsigned char* __restrict__ mask, const float* __restrict__ e1,
    const float* __restrict__ e2, const float* __restrict__ Lr,
    const float* __restrict__ Dr, const short* __restrict__ Bt,
    float* __restrict__ attnw, float* __restrict__ C)
{
  __shared__ short As0[32 * 32],  As1[32 * 32];     // 2 x 2 KB
  __shared__ short Bs0[256 * 32], Bs1[256 * 32];    // 2 x 16 KB
  __shared__ float e2s[2048];                       // 8 KB
  __shared__ unsigned char msk[32 * 256];           // 8 KB
  const int bid = blockIdx.x;
  const int bz  = bid & 7;          // XCD-pinned batch
  const int M0  = (bid >> 3) << 5;
  const int tid = threadIdx.x;
  const int w = tid >> 6, lane = tid & 63;
  const int g = lane >> 4, lr = lane & 15;

  const long long rb = (long long)bz * 2048;
  Bt    += (long long)bz * 524288;
  attnw += (long long)bz * 4194304;
  C     += (long long)bz * 524288;

  const int pr = tid >> 3, k4 = (tid & 7) << 2;
  const int prow = M0 + pr;
  const float E1p = e1[rb + prow];
  const float Lp  = Lr[rb + prow];
  const float Dp  = Dr[rb + prow];
  float* arow = attnw + (long long)prow * 2048;
  const int kc = k4 >> 3;
  const int as_off = pr * 32 + ((kc ^ ((pr >> 1) & 3)) << 3) + (k4 & 7);

  const int bcol_off = lane >> 2;
  const int bchunk   = (lane & 3) ^ ((lane >> 3) & 3);

  // ---- prologue: hoist e2 row (8 KB) + 32 mask rows (8 KB); 1024 B per issue ----
  {
    const float* e2g = e2 + rb;
    const unsigned char* mg = mask + (rb + M0) * 256;
#pragma unroll
    for (int q = 0; q < 2; ++q) {
      int p = w * 2 + q;                                // 0..7, wave-uniform
      gload16(e2g + p * 256 + lane * 4, (char*)e2s + p * 1024);
      gload16(mg  + p * 1024 + lane * 16, (char*)msk + p * 1024);
    }
  }

  f32x4 acc[2][4] = {};

  auto STAGE = [&](short* BsD, short* AsD, int k0) {
#pragma unroll
    for (int q = 0; q < 4; ++q) {
      int pp = w * 4 + q;
      int col = pp * 16 + bcol_off;
      gload16(Bt + (long long)col * 2048 + k0 + bchunk * 8, BsD + pp * 512);
    }
    const int kk = k0 + k4;
    const unsigned by = (unsigned)(msk[pr * 256 + (kk >> 3)] >> (k4 & 7)) & 0xFu;
    float4v ev = *(const float4v*)(e2s + kk);
    float p4[4];
#pragma unroll
    for (int e = 0; e < 4; ++e) {
      float x = E1p + ev[e];
      float v = fmaxf(x, LRELU_ALPHA * x);
      float P = __builtin_amdgcn_exp2f(fmaf(v, Lp, Dp));
      p4[e] = ((by >> e) & 1u) ? P : 0.0f;
    }
    float4v o;
#pragma unroll
    for (int e = 0; e < 4; ++e) o[e] = p4[e];
    *(float4v*)(arow + kk) = o;                    // attention (f32), once
    uint2v uv;
    uv[0] = cvtpk_bf16(p4[0], p4[1]);
    uv[1] = cvtpk_bf16(p4[2], p4[3]);
    *(uint2v*)(AsD + as_off) = uv;
  };

  auto COMPUTE = [&](const short* BsD, const short* AsD) {
    bf16x8 af[2], bfr[4];
#pragma unroll
    for (int i = 0; i < 2; ++i) {
      int row = i * 16 + lr;
      af[i] = *(const bf16x8*)(AsD + row * 32 + ((g ^ ((row >> 1) & 3)) << 3));
    }
#pragma unroll
    for (int j = 0; j < 4; ++j) {
      int col = w * 64 + j * 16 + lr;
      bfr[j] = *(const bf16x8*)(BsD + col * 32 + ((g ^ ((col >> 1) & 3)) << 3));
    }
    __builtin_amdgcn_s_setprio(1);                 // T5: favor MFMA-phase waves
#pragma unroll
    for (int i = 0; i < 2; ++i)
#pragma unroll
      for (int j = 0; j < 4; ++j)
        acc[i][j] = __builtin_amdgcn_mfma_f32_16x16x32_bf16(af[i], bfr[j], acc[i][j], 0, 0, 0);
    __builtin_amdgcn_s_setprio(0);
  };

  __syncthreads();                 // e2s/msk staged (barrier drains vmcnt)
  STAGE(Bs0, As0, 0);
  __syncthreads();
  for (int t = 0; t < 64; t += 2) {
    STAGE(Bs1, As1, (t + 1) * 32);
    COMPUTE(Bs0, As0);
    __syncthreads();
    if (t + 2 < 64) STAGE(Bs0, As0, (t + 2) * 32);
    COMPUTE(Bs1, As1);
    __syncthreads();
  }

  // C/D: col=lane&15, row=(lane>>4)*4+reg  [m89]
#pragma unroll
  for (int i = 0; i < 2; ++i) {
    int row_base = M0 + i * 16 + 4 * g;
#pragma unroll
    for (int j = 0; j < 4; ++j) {
      int col = w * 64 + j * 16 + lr;
#pragma unroll
      for (int r = 0; r < 4; ++r) {
        float v = acc[i][j][r];
        v = (v > 0.f) ? v : (__expf(v) - 1.f);   // ELU
        C[(long long)(row_base + r) * 256 + col] = v;
      }
    }
  }
}

extern "C" void kernel_launch(void* const* d_in, const int* in_sizes, int n_in,
                              void* d_out, int out_size, void* d_ws, size_t ws_size,
                              hipStream_t stream)
{
  const float* h   = (const float*)d_in[0];   // (8,2048,256) f32
  const int*   adj = (const int*)d_in[1];     // (8,2048,2048) int32
  const float* W   = (const float*)d_in[2];   // (256,256) f32
  const float* a   = (const float*)d_in[3];   // (512,1) f32

  float* hp_out   = (float*)d_out;            // elu(h_prime): 4,194,304 f32
  float* attn_out = hp_out + 4194304LL;       // attention: 33,554,432 f32

  // workspace: ~13.0 MB (R12-proven layout)
  unsigned char* mask = (unsigned char*)d_ws; // 4.19 MB
  short* W_t  = (short*)(mask + 4194304);     // 256x256 bf16
  short* Wh_t = W_t + 65536;                  // 8 x (256x2048) bf16
  float* e1   = (float*)(Wh_t + 4194304);     // 16384
  float* e2   = e1 + 16384;
  float* Lr   = e2 + 16384;
  float* Dr   = Lr + 16384;
  float* aW1  = Dr + 16384;                   // 256
  float* aW2  = aW1 + 256;                    // 256

  // 1) W^T (bf16) + aW1/aW2 = W @ a1/a2
  prep_kernel<<<17, 256, 0, stream>>>(W, a, W_t, aW1, aW2);
  // 2) Wh_t = (cast(h) @ W)^T with fused e1/e2 = h @ aW
  gemm_h_kernel<<<dim3(128, 2), 256, 0, stream>>>(h, W_t, Wh_t, aW1, aW2, e1, e2);
  // 3) adj -> bitmask + per-row (L,D)  (high-TLP, coalesced)
  pack_stats_kernel<<<dim3(2048, 8), 256, 0, stream>>>(adj, e1, e2, mask, Lr, Dr);
  // 4) pipelined pv (R12-exact + T5 setprio): attention write + P @ Wh_t + ELU
  pv_kernel<<<512, 256, 0, stream>>>(mask, e1, e2, Lr, Dr, Wh_t, attn_out, hp_out);
}